// Round 3
// baseline (288.890 us; speedup 1.0000x reference)
//
#include <hip/hip_runtime.h>

#define RES   256
#define NCH   128   // C*F
#define NC    16
#define QG    32    // channels per transpose block
#define NPK   64    // packed uint32 per (p,y,x) position = NCH/2
#define NBINS 4096  // 16^3 Morton cells

__device__ __forceinline__ unsigned int f32_to_bf16_rne(float f) {
    unsigned int u = __float_as_uint(f);
    return (u + 0x7FFFu + ((u >> 16) & 1u)) >> 16;
}
__device__ __forceinline__ float bf16_lo(unsigned int w) {
    return __uint_as_float(w << 16);
}
__device__ __forceinline__ float bf16_hi(unsigned int w) {
    return __uint_as_float(w & 0xFFFF0000u);
}
__device__ __forceinline__ float reflectf(float v) {
    float r = fabsf(v);
    r = fmodf(r, 510.0f);                 // m = 2*(RES-1)
    return (r > 255.0f) ? (510.0f - r) : r;
}
__device__ __forceinline__ unsigned spread3(unsigned v) { // 4-bit -> stride-3
    return (v & 1u) | ((v & 2u) << 2) | ((v & 4u) << 4) | ((v & 8u) << 6);
}
__device__ __forceinline__ int point_cell(const float* __restrict__ coords, int i) {
    const float r0 = reflectf((coords[3 * (size_t)i + 0] + 1.0f) * 127.5f);
    const float r1 = reflectf((coords[3 * (size_t)i + 1] + 1.0f) * 127.5f);
    const float r2 = reflectf((coords[3 * (size_t)i + 2] + 1.0f) * 127.5f);
    const unsigned cx = (unsigned)min(max((int)r0, 0), 255) >> 4;
    const unsigned cy = (unsigned)min(max((int)r1, 0), 255) >> 4;
    const unsigned cz = (unsigned)min(max((int)r2, 0), 255) >> 4;
    return (int)(spread3(cx) | (spread3(cy) << 1) | (spread3(cz) << 2));
}

// ---------------------------------------------------------------------------
// Transpose+pack: f32 [3][128][256][256] -> bf16-pair uint32 [3][256][256][64]
// ---------------------------------------------------------------------------
__global__ __launch_bounds__(256) void fg_transpose_bf16(
    const float* __restrict__ in, unsigned int* __restrict__ out)
{
    __shared__ float tile[QG][RES + 4];   // row stride 260 words: 16B-aligned rows
    const int tid = threadIdx.x;
    const int qg = blockIdx.x;            // 0..3
    const int y  = blockIdx.y;            // 0..255
    const int p  = blockIdx.z;            // 0..2
    const int q0 = qg * QG;

    const float* src = in + (((size_t)p * NCH + q0) * RES + y) * RES;
    #pragma unroll
    for (int it = 0; it < (QG * RES / 4) / 256; ++it) {   // 8 iters, float4 rows
        const int lin = it * 256 + tid;
        const int qq = lin >> 6;          // row within group
        const int x4 = lin & 63;          // float4 index within row
        *(float4*)&tile[qq][x4 * 4] =
            *(const float4*)(src + (size_t)qq * (RES * RES) + x4 * 4);
    }
    __syncthreads();
    unsigned int* dst = out + (((size_t)p * RES + y) * RES) * NPK + (q0 >> 1);
    #pragma unroll
    for (int it = 0; it < (RES * (QG / 2)) / 256; ++it) {  // 16 iters
        const int lin = it * 256 + tid;
        const int qp = lin & 15;          // packed-pair index within group
        const int x  = lin >> 4;
        const unsigned int lo = f32_to_bf16_rne(tile[2 * qp + 0][x]);
        const unsigned int hi = f32_to_bf16_rne(tile[2 * qp + 1][x]);
        dst[(size_t)x * NPK + qp] = lo | (hi << 16);
    }
}

// ---------------------------------------------------------------------------
// Sort pass 1: Morton-cell histogram
// ---------------------------------------------------------------------------
__global__ __launch_bounds__(256) void fg_hist(
    const float* __restrict__ coords, unsigned* __restrict__ hist, int n)
{
    const int i = blockIdx.x * 256 + threadIdx.x;
    if (i >= n) return;
    atomicAdd(&hist[point_cell(coords, i)], 1u);
}

// ---------------------------------------------------------------------------
// Sort pass 2: exclusive scan over 4096 bins (one block) + frp precompute
// ---------------------------------------------------------------------------
__global__ __launch_bounds__(256) void fg_scan(
    const unsigned* __restrict__ hist, unsigned* __restrict__ cursor,
    const float* __restrict__ freqs, float* __restrict__ frp)
{
    __shared__ unsigned s[256];
    const int t = threadIdx.x;
    unsigned loc[16];
    unsigned sum = 0;
    #pragma unroll
    for (int k = 0; k < 16; ++k) { loc[k] = hist[t * 16 + k]; sum += loc[k]; }
    s[t] = sum;
    __syncthreads();
    for (int off = 1; off < 256; off <<= 1) {
        unsigned v = (t >= off) ? s[t - off] : 0u;
        __syncthreads();
        s[t] += v;
        __syncthreads();
    }
    unsigned base = (t == 0) ? 0u : s[t - 1];
    #pragma unroll
    for (int k = 0; k < 16; ++k) { cursor[t * 16 + k] = base; base += loc[k]; }
    if (t < 128) {
        const float f = fminf(fmaxf(freqs[t], 0.0f), 1.0f);
        frp[t] = __builtin_amdgcn_exp2f(f * 8.0f) - 0.5f;
    }
}

// ---------------------------------------------------------------------------
// Sort pass 3: scatter point indices into Morton order
// ---------------------------------------------------------------------------
__global__ __launch_bounds__(256) void fg_scatter(
    const float* __restrict__ coords, unsigned* __restrict__ cursor,
    unsigned* __restrict__ perm, int n)
{
    const int i = blockIdx.x * 256 + threadIdx.x;
    if (i >= n) return;
    const unsigned pos = atomicAdd(&cursor[point_cell(coords, i)], 1u);
    perm[pos] = (unsigned)i;
}

// ---------------------------------------------------------------------------
// Main kernel (packed bf16 grid, Morton-sorted point order)
// ---------------------------------------------------------------------------
__global__ __launch_bounds__(256) void fg_main_bf16(
    const float* __restrict__ coords,
    const unsigned int* __restrict__ grid,   // [3][256][256][64]
    const float* __restrict__ frp_in,        // 128 precomputed (fr+0.5)
    const unsigned* __restrict__ perm,
    float* __restrict__ out, int n)
{
    const int t = threadIdx.x;
    const int c = t & 15;                        // output channel 0..15
    const int slot = blockIdx.x * 16 + (t >> 4); // sorted slot
    if (slot >= n) return;
    const int i = (int)perm[slot];               // original point index

    float frp[8];
    *(float4*)(frp + 0) = *(const float4*)(frp_in + c * 8 + 0);
    *(float4*)(frp + 4) = *(const float4*)(frp_in + c * 8 + 4);

    const float c0 = coords[3 * (size_t)i + 0];
    const float c1 = coords[3 * (size_t)i + 1];
    const float c2 = coords[3 * (size_t)i + 2];
    const float pts0 = (c0 + 1.0f) * 127.5f;
    const float pts1 = (c1 + 1.0f) * 127.5f;
    const float pts2 = (c2 + 1.0f) * 127.5f;

    float acc = 0.0f;

    #pragma unroll
    for (int p = 0; p < 3; ++p) {
        // plane 0 samples (y,z); plane 1 (x,z); plane 2 (x,y)
        const float sx = (p == 0) ? pts1 : pts0;
        const float sy = (p == 2) ? pts1 : pts2;
        const float pp = (p == 0) ? pts0 : ((p == 1) ? pts1 : pts2);

        const float ix = reflectf(sx);
        const float iy = reflectf(sy);
        const float x0f = floorf(ix), y0f = floorf(iy);
        const float wx = ix - x0f, wy = iy - y0f;
        int x0 = (int)x0f; x0 = min(max(x0, 0), RES - 1);
        int y0 = (int)y0f; y0 = min(max(y0, 0), RES - 1);
        const int x1 = min(x0 + 1, RES - 1);
        const int y1 = min(y0 + 1, RES - 1);
        const float w00 = (1.0f - wx) * (1.0f - wy);
        const float w01 = wx * (1.0f - wy);
        const float w10 = (1.0f - wx) * wy;
        const float w11 = wx * wy;
        // phase in revolutions: (pts+0.5)*(fr+0.5)/512  ->  v_cos(2*pi*rev)
        const float A = (pp + 0.5f) * (1.0f / 512.0f);

        const size_t rowbase = ((size_t)p * RES) * RES;
        const unsigned int* b00 = grid + (rowbase + (size_t)y0 * RES + x0) * NPK + c * 4;
        const unsigned int* b01 = grid + (rowbase + (size_t)y0 * RES + x1) * NPK + c * 4;
        const unsigned int* b10 = grid + (rowbase + (size_t)y1 * RES + x0) * NPK + c * 4;
        const unsigned int* b11 = grid + (rowbase + (size_t)y1 * RES + x1) * NPK + c * 4;
        const uint4 g00 = *(const uint4*)b00;
        const uint4 g01 = *(const uint4*)b01;
        const uint4 g10 = *(const uint4*)b10;
        const uint4 g11 = *(const uint4*)b11;
        const unsigned int w0[4] = {g00.x, g00.y, g00.z, g00.w};
        const unsigned int w1[4] = {g01.x, g01.y, g01.z, g01.w};
        const unsigned int w2[4] = {g10.x, g10.y, g10.z, g10.w};
        const unsigned int w3[4] = {g11.x, g11.y, g11.z, g11.w};

        #pragma unroll
        for (int jj = 0; jj < 4; ++jj) {
            const float clo = w00 * bf16_lo(w0[jj]) + w01 * bf16_lo(w1[jj])
                            + w10 * bf16_lo(w2[jj]) + w11 * bf16_lo(w3[jj]);
            const float chi = w00 * bf16_hi(w0[jj]) + w01 * bf16_hi(w1[jj])
                            + w10 * bf16_hi(w2[jj]) + w11 * bf16_hi(w3[jj]);
            const float rl = __builtin_amdgcn_fractf(A * frp[2 * jj + 0]);
            const float rh = __builtin_amdgcn_fractf(A * frp[2 * jj + 1]);
            acc += clo * __builtin_amdgcn_cosf(rl);
            acc += chi * __builtin_amdgcn_cosf(rh);
        }
    }

    out[(size_t)i * NC + c] = 2.0f * acc;
}

// Fallback (no workspace): direct f32 channel-major gather.
__global__ __launch_bounds__(256) void fg_main_f32(
    const float* __restrict__ coords,
    const float* __restrict__ grid,
    const float* __restrict__ freqs,
    float* __restrict__ out, int n)
{
    const int t = threadIdx.x;
    const int c = t & 15;
    const int i = blockIdx.x * 16 + (t >> 4);
    if (i >= n) return;

    float frp[8];
    #pragma unroll
    for (int j = 0; j < 8; ++j) {
        float f = fminf(fmaxf(freqs[c * 8 + j], 0.0f), 1.0f);
        frp[j] = __builtin_amdgcn_exp2f(f * 8.0f) - 0.5f;
    }
    const float c0 = coords[3 * (size_t)i + 0];
    const float c1 = coords[3 * (size_t)i + 1];
    const float c2 = coords[3 * (size_t)i + 2];
    const float pts0 = (c0 + 1.0f) * 127.5f;
    const float pts1 = (c1 + 1.0f) * 127.5f;
    const float pts2 = (c2 + 1.0f) * 127.5f;
    float acc = 0.0f;
    #pragma unroll
    for (int p = 0; p < 3; ++p) {
        const float sx = (p == 0) ? pts1 : pts0;
        const float sy = (p == 2) ? pts1 : pts2;
        const float pp = (p == 0) ? pts0 : ((p == 1) ? pts1 : pts2);
        const float ix = reflectf(sx);
        const float iy = reflectf(sy);
        const float x0f = floorf(ix), y0f = floorf(iy);
        const float wx = ix - x0f, wy = iy - y0f;
        int x0 = (int)x0f; x0 = min(max(x0, 0), RES - 1);
        int y0 = (int)y0f; y0 = min(max(y0, 0), RES - 1);
        const int x1 = min(x0 + 1, RES - 1);
        const int y1 = min(y0 + 1, RES - 1);
        const float w00 = (1.0f - wx) * (1.0f - wy);
        const float w01 = wx * (1.0f - wy);
        const float w10 = (1.0f - wx) * wy;
        const float w11 = wx * wy;
        const float A = (pp + 0.5f) * (1.0f / 512.0f);
        const size_t plane = (size_t)p * NCH * RES * RES;
        const int o00 = y0 * RES + x0, o01 = y0 * RES + x1;
        const int o10 = y1 * RES + x0, o11 = y1 * RES + x1;
        #pragma unroll
        for (int j = 0; j < 8; ++j) {
            const float* gq = grid + plane + (size_t)(c * 8 + j) * (RES * RES);
            const float coef = w00 * gq[o00] + w01 * gq[o01]
                             + w10 * gq[o10] + w11 * gq[o11];
            const float rr = __builtin_amdgcn_fractf(A * frp[j]);
            acc += coef * __builtin_amdgcn_cosf(rr);
        }
    }
    out[(size_t)i * NC + c] = 2.0f * acc;
}

extern "C" void kernel_launch(void* const* d_in, const int* in_sizes, int n_in,
                              void* d_out, int out_size, void* d_ws, size_t ws_size,
                              hipStream_t stream)
{
    const float* coords = (const float*)d_in[0];
    const float* grid   = (const float*)d_in[1];
    const float* freqs  = (const float*)d_in[2];
    float* out = (float*)d_out;
    const int n = in_sizes[0] / 3;

    // Workspace layout (all 16B-aligned)
    const size_t gridT_b  = (size_t)3 * RES * RES * NPK * sizeof(unsigned); // 50.33 MB
    const size_t hist_b   = (size_t)NBINS * sizeof(unsigned);
    const size_t frp_b    = 128 * sizeof(float);
    const size_t perm_b   = (size_t)((n + 3) & ~3) * sizeof(unsigned);
    const size_t need = gridT_b + 2 * hist_b + frp_b + perm_b;

    const int blocks = (n + 15) / 16;

    if (ws_size >= need) {
        char* ws = (char*)d_ws;
        unsigned* gridT  = (unsigned*)ws;                 ws += gridT_b;
        unsigned* hist   = (unsigned*)ws;                 ws += hist_b;
        unsigned* cursor = (unsigned*)ws;                 ws += hist_b;
        float*    frp    = (float*)ws;                    ws += frp_b;
        unsigned* perm   = (unsigned*)ws;

        hipMemsetAsync(hist, 0, hist_b, stream);
        hipLaunchKernelGGL(fg_hist, dim3((n + 255) / 256), dim3(256), 0, stream,
                           coords, hist, n);
        hipLaunchKernelGGL(fg_scan, dim3(1), dim3(256), 0, stream,
                           hist, cursor, freqs, frp);
        hipLaunchKernelGGL(fg_scatter, dim3((n + 255) / 256), dim3(256), 0, stream,
                           coords, cursor, perm, n);
        hipLaunchKernelGGL(fg_transpose_bf16, dim3(4, RES, 3), dim3(256), 0, stream,
                           grid, gridT);
        hipLaunchKernelGGL(fg_main_bf16, dim3(blocks), dim3(256), 0, stream,
                           coords, gridT, frp, perm, out, n);
    } else {
        hipLaunchKernelGGL(fg_main_f32, dim3(blocks), dim3(256), 0, stream,
                           coords, grid, freqs, out, n);
    }
}

// Round 4
// 244.328 us; speedup vs baseline: 1.1824x; 1.1824x over previous
//
#include <hip/hip_runtime.h>

#define RES   256
#define NCH   128   // C*F
#define NC    16
#define QG    32    // channels per transpose block
#define NPK   64    // packed uint32 per (p,y,x) position = NCH/2
#define NBINS 4096  // 16^3 Morton cells
#define TBLK  3072  // transpose grid size (4*256*3)

__device__ __forceinline__ unsigned int f32_to_bf16_rne(float f) {
    unsigned int u = __float_as_uint(f);
    return (u + 0x7FFFu + ((u >> 16) & 1u)) >> 16;
}
__device__ __forceinline__ float bf16_lo(unsigned int w) {
    return __uint_as_float(w << 16);
}
__device__ __forceinline__ float bf16_hi(unsigned int w) {
    return __uint_as_float(w & 0xFFFF0000u);
}
__device__ __forceinline__ float reflectf(float v) {
    float r = fabsf(v);
    r = fmodf(r, 510.0f);                 // m = 2*(RES-1)
    return (r > 255.0f) ? (510.0f - r) : r;
}
__device__ __forceinline__ unsigned spread3(unsigned v) { // 4-bit -> stride-3
    return (v & 1u) | ((v & 2u) << 2) | ((v & 4u) << 4) | ((v & 8u) << 6);
}
__device__ __forceinline__ int point_cell(const float* __restrict__ coords, int i) {
    const float r0 = reflectf((coords[3 * (size_t)i + 0] + 1.0f) * 127.5f);
    const float r1 = reflectf((coords[3 * (size_t)i + 1] + 1.0f) * 127.5f);
    const float r2 = reflectf((coords[3 * (size_t)i + 2] + 1.0f) * 127.5f);
    const unsigned cx = (unsigned)min(max((int)r0, 0), 255) >> 4;
    const unsigned cy = (unsigned)min(max((int)r1, 0), 255) >> 4;
    const unsigned cz = (unsigned)min(max((int)r2, 0), 255) >> 4;
    return (int)(spread3(cx) | (spread3(cy) << 1) | (spread3(cz) << 2));
}

// ---------------------------------------------------------------------------
// Transpose+pack f32 [3][128][256][256] -> bf16-pair uint32 [3][256][256][64],
// FUSED with Morton-cell histogram (saves a dispatch; atomics hide behind
// the transpose's memory traffic).
// ---------------------------------------------------------------------------
__global__ __launch_bounds__(256) void fg_transpose_hist(
    const float* __restrict__ in, unsigned int* __restrict__ out,
    const float* __restrict__ coords, unsigned* __restrict__ hist, int n)
{
    __shared__ float tile[QG][RES + 4];   // row stride 260 words: 16B-aligned rows
    const int tid = threadIdx.x;
    const int qg = blockIdx.x;            // 0..3
    const int y  = blockIdx.y;            // 0..255
    const int p  = blockIdx.z;            // 0..2

    // --- histogram slice for this block ---
    {
        const int bid = (p * RES + y) * 4 + qg;          // 0..3071
        const int per = (n + TBLK - 1) / TBLK;           // 86 for n=262144
        const int s0 = bid * per;
        const int s1 = min(s0 + per, n);
        for (int k = s0 + tid; k < s1; k += 256)
            atomicAdd(&hist[point_cell(coords, k)], 1u);
    }

    const int q0 = qg * QG;
    const float* src = in + (((size_t)p * NCH + q0) * RES + y) * RES;
    #pragma unroll
    for (int it = 0; it < (QG * RES / 4) / 256; ++it) {   // 8 iters, float4 rows
        const int lin = it * 256 + tid;
        const int qq = lin >> 6;          // row within group
        const int x4 = lin & 63;          // float4 index within row
        *(float4*)&tile[qq][x4 * 4] =
            *(const float4*)(src + (size_t)qq * (RES * RES) + x4 * 4);
    }
    __syncthreads();
    unsigned int* dst = out + (((size_t)p * RES + y) * RES) * NPK + (q0 >> 1);
    #pragma unroll
    for (int it = 0; it < (RES * (QG / 2)) / 256; ++it) {  // 16 iters
        const int lin = it * 256 + tid;
        const int qp = lin & 15;          // packed-pair index within group
        const int x  = lin >> 4;
        const unsigned int lo = f32_to_bf16_rne(tile[2 * qp + 0][x]);
        const unsigned int hi = f32_to_bf16_rne(tile[2 * qp + 1][x]);
        dst[(size_t)x * NPK + qp] = lo | (hi << 16);
    }
}

// ---------------------------------------------------------------------------
// Exclusive scan over 4096 bins (one block, wave-shuffle prefix, 1 barrier)
// + frp precompute
// ---------------------------------------------------------------------------
__global__ __launch_bounds__(256) void fg_scan(
    const unsigned* __restrict__ hist, unsigned* __restrict__ cursor,
    const float* __restrict__ freqs, float* __restrict__ frp)
{
    __shared__ unsigned wtot[4];
    const int t = threadIdx.x;
    const int lane = t & 63;
    const int wid = t >> 6;
    unsigned loc[16];
    unsigned sum = 0;
    #pragma unroll
    for (int k = 0; k < 16; ++k) { loc[k] = hist[t * 16 + k]; sum += loc[k]; }
    // wave-inclusive scan of sum
    unsigned v = sum;
    #pragma unroll
    for (int off = 1; off < 64; off <<= 1) {
        unsigned u = __shfl_up(v, off);
        if (lane >= off) v += u;
    }
    if (lane == 63) wtot[wid] = v;
    __syncthreads();
    unsigned base = 0;
    #pragma unroll
    for (int w = 0; w < 4; ++w) base += (w < wid) ? wtot[w] : 0u;
    unsigned run = base + (v - sum);      // exclusive prefix for this thread
    #pragma unroll
    for (int k = 0; k < 16; ++k) { cursor[t * 16 + k] = run; run += loc[k]; }
    if (t < 128) {
        const float f = fminf(fmaxf(freqs[t], 0.0f), 1.0f);
        frp[t] = __builtin_amdgcn_exp2f(f * 8.0f) - 0.5f;
    }
}

// ---------------------------------------------------------------------------
// Scatter point indices into Morton order
// ---------------------------------------------------------------------------
__global__ __launch_bounds__(256) void fg_scatter(
    const float* __restrict__ coords, unsigned* __restrict__ cursor,
    unsigned* __restrict__ perm, int n)
{
    const int i = blockIdx.x * 256 + threadIdx.x;
    if (i >= n) return;
    const unsigned pos = atomicAdd(&cursor[point_cell(coords, i)], 1u);
    perm[pos] = (unsigned)i;
}

// ---------------------------------------------------------------------------
// Main kernel (packed bf16 grid, Morton-sorted points, XCD-chunk swizzle:
// each XCD gets a CONTIGUOUS Morton range so its private L2 sees a compact,
// slowly-moving working set instead of round-robin-shredded cells).
// ---------------------------------------------------------------------------
__global__ __launch_bounds__(256) void fg_main_bf16(
    const float* __restrict__ coords,
    const unsigned int* __restrict__ grid,   // [3][256][256][64]
    const float* __restrict__ frp_in,        // 128 precomputed (fr+0.5)
    const unsigned* __restrict__ perm,
    float* __restrict__ out, int n)
{
    const int t = threadIdx.x;
    const int c = t & 15;                        // output channel 0..15
    int b = blockIdx.x;
    {
        const int G = gridDim.x;
        const int chunk = G >> 3;
        const int lim = chunk << 3;
        if (b < lim) b = (b & 7) * chunk + (b >> 3);  // undo round-robin
    }
    const int slot = b * 16 + (t >> 4);          // sorted slot
    if (slot >= n) return;
    const int i = (int)perm[slot];               // original point index

    float frp[8];
    *(float4*)(frp + 0) = *(const float4*)(frp_in + c * 8 + 0);
    *(float4*)(frp + 4) = *(const float4*)(frp_in + c * 8 + 4);

    const float c0 = coords[3 * (size_t)i + 0];
    const float c1 = coords[3 * (size_t)i + 1];
    const float c2 = coords[3 * (size_t)i + 2];
    const float pts0 = (c0 + 1.0f) * 127.5f;
    const float pts1 = (c1 + 1.0f) * 127.5f;
    const float pts2 = (c2 + 1.0f) * 127.5f;

    float acc = 0.0f;

    #pragma unroll
    for (int p = 0; p < 3; ++p) {
        // plane 0 samples (y,z); plane 1 (x,z); plane 2 (x,y)
        const float sx = (p == 0) ? pts1 : pts0;
        const float sy = (p == 2) ? pts1 : pts2;
        const float pp = (p == 0) ? pts0 : ((p == 1) ? pts1 : pts2);

        const float ix = reflectf(sx);
        const float iy = reflectf(sy);
        const float x0f = floorf(ix), y0f = floorf(iy);
        const float wx = ix - x0f, wy = iy - y0f;
        int x0 = (int)x0f; x0 = min(max(x0, 0), RES - 1);
        int y0 = (int)y0f; y0 = min(max(y0, 0), RES - 1);
        const int x1 = min(x0 + 1, RES - 1);
        const int y1 = min(y0 + 1, RES - 1);
        const float w00 = (1.0f - wx) * (1.0f - wy);
        const float w01 = wx * (1.0f - wy);
        const float w10 = (1.0f - wx) * wy;
        const float w11 = wx * wy;
        // phase in revolutions: (pts+0.5)*(fr+0.5)/512  ->  v_cos(2*pi*rev)
        const float A = (pp + 0.5f) * (1.0f / 512.0f);

        const size_t rowbase = ((size_t)p * RES) * RES;
        const unsigned int* b00 = grid + (rowbase + (size_t)y0 * RES + x0) * NPK + c * 4;
        const unsigned int* b01 = grid + (rowbase + (size_t)y0 * RES + x1) * NPK + c * 4;
        const unsigned int* b10 = grid + (rowbase + (size_t)y1 * RES + x0) * NPK + c * 4;
        const unsigned int* b11 = grid + (rowbase + (size_t)y1 * RES + x1) * NPK + c * 4;
        const uint4 g00 = *(const uint4*)b00;
        const uint4 g01 = *(const uint4*)b01;
        const uint4 g10 = *(const uint4*)b10;
        const uint4 g11 = *(const uint4*)b11;
        const unsigned int w0[4] = {g00.x, g00.y, g00.z, g00.w};
        const unsigned int w1[4] = {g01.x, g01.y, g01.z, g01.w};
        const unsigned int w2[4] = {g10.x, g10.y, g10.z, g10.w};
        const unsigned int w3[4] = {g11.x, g11.y, g11.z, g11.w};

        #pragma unroll
        for (int jj = 0; jj < 4; ++jj) {
            const float clo = w00 * bf16_lo(w0[jj]) + w01 * bf16_lo(w1[jj])
                            + w10 * bf16_lo(w2[jj]) + w11 * bf16_lo(w3[jj]);
            const float chi = w00 * bf16_hi(w0[jj]) + w01 * bf16_hi(w1[jj])
                            + w10 * bf16_hi(w2[jj]) + w11 * bf16_hi(w3[jj]);
            const float rl = __builtin_amdgcn_fractf(A * frp[2 * jj + 0]);
            const float rh = __builtin_amdgcn_fractf(A * frp[2 * jj + 1]);
            acc += clo * __builtin_amdgcn_cosf(rl);
            acc += chi * __builtin_amdgcn_cosf(rh);
        }
    }

    out[(size_t)i * NC + c] = 2.0f * acc;
}

// Fallback (no workspace): direct f32 channel-major gather.
__global__ __launch_bounds__(256) void fg_main_f32(
    const float* __restrict__ coords,
    const float* __restrict__ grid,
    const float* __restrict__ freqs,
    float* __restrict__ out, int n)
{
    const int t = threadIdx.x;
    const int c = t & 15;
    const int i = blockIdx.x * 16 + (t >> 4);
    if (i >= n) return;

    float frp[8];
    #pragma unroll
    for (int j = 0; j < 8; ++j) {
        float f = fminf(fmaxf(freqs[c * 8 + j], 0.0f), 1.0f);
        frp[j] = __builtin_amdgcn_exp2f(f * 8.0f) - 0.5f;
    }
    const float c0 = coords[3 * (size_t)i + 0];
    const float c1 = coords[3 * (size_t)i + 1];
    const float c2 = coords[3 * (size_t)i + 2];
    const float pts0 = (c0 + 1.0f) * 127.5f;
    const float pts1 = (c1 + 1.0f) * 127.5f;
    const float pts2 = (c2 + 1.0f) * 127.5f;
    float acc = 0.0f;
    #pragma unroll
    for (int p = 0; p < 3; ++p) {
        const float sx = (p == 0) ? pts1 : pts0;
        const float sy = (p == 2) ? pts1 : pts2;
        const float pp = (p == 0) ? pts0 : ((p == 1) ? pts1 : pts2);
        const float ix = reflectf(sx);
        const float iy = reflectf(sy);
        const float x0f = floorf(ix), y0f = floorf(iy);
        const float wx = ix - x0f, wy = iy - y0f;
        int x0 = (int)x0f; x0 = min(max(x0, 0), RES - 1);
        int y0 = (int)y0f; y0 = min(max(y0, 0), RES - 1);
        const int x1 = min(x0 + 1, RES - 1);
        const int y1 = min(y0 + 1, RES - 1);
        const float w00 = (1.0f - wx) * (1.0f - wy);
        const float w01 = wx * (1.0f - wy);
        const float w10 = (1.0f - wx) * wy;
        const float w11 = wx * wy;
        const float A = (pp + 0.5f) * (1.0f / 512.0f);
        const size_t plane = (size_t)p * NCH * RES * RES;
        const int o00 = y0 * RES + x0, o01 = y0 * RES + x1;
        const int o10 = y1 * RES + x0, o11 = y1 * RES + x1;
        #pragma unroll
        for (int j = 0; j < 8; ++j) {
            const float* gq = grid + plane + (size_t)(c * 8 + j) * (RES * RES);
            const float coef = w00 * gq[o00] + w01 * gq[o01]
                             + w10 * gq[o10] + w11 * gq[o11];
            const float rr = __builtin_amdgcn_fractf(A * frp[j]);
            acc += coef * __builtin_amdgcn_cosf(rr);
        }
    }
    out[(size_t)i * NC + c] = 2.0f * acc;
}

extern "C" void kernel_launch(void* const* d_in, const int* in_sizes, int n_in,
                              void* d_out, int out_size, void* d_ws, size_t ws_size,
                              hipStream_t stream)
{
    const float* coords = (const float*)d_in[0];
    const float* grid   = (const float*)d_in[1];
    const float* freqs  = (const float*)d_in[2];
    float* out = (float*)d_out;
    const int n = in_sizes[0] / 3;

    // Workspace layout (all 16B-aligned)
    const size_t gridT_b  = (size_t)3 * RES * RES * NPK * sizeof(unsigned); // 50.33 MB
    const size_t hist_b   = (size_t)NBINS * sizeof(unsigned);
    const size_t frp_b    = 128 * sizeof(float);
    const size_t perm_b   = (size_t)((n + 3) & ~3) * sizeof(unsigned);
    const size_t need = gridT_b + 2 * hist_b + frp_b + perm_b;

    const int blocks = (n + 15) / 16;

    if (ws_size >= need) {
        char* ws = (char*)d_ws;
        unsigned* gridT  = (unsigned*)ws;                 ws += gridT_b;
        unsigned* hist   = (unsigned*)ws;                 ws += hist_b;
        unsigned* cursor = (unsigned*)ws;                 ws += hist_b;
        float*    frp    = (float*)ws;                    ws += frp_b;
        unsigned* perm   = (unsigned*)ws;

        hipMemsetAsync(hist, 0, hist_b, stream);
        hipLaunchKernelGGL(fg_transpose_hist, dim3(4, RES, 3), dim3(256), 0, stream,
                           grid, gridT, coords, hist, n);
        hipLaunchKernelGGL(fg_scan, dim3(1), dim3(256), 0, stream,
                           hist, cursor, freqs, frp);
        hipLaunchKernelGGL(fg_scatter, dim3((n + 255) / 256), dim3(256), 0, stream,
                           coords, cursor, perm, n);
        hipLaunchKernelGGL(fg_main_bf16, dim3(blocks), dim3(256), 0, stream,
                           coords, gridT, frp, perm, out, n);
    } else {
        hipLaunchKernelGGL(fg_main_f32, dim3(blocks), dim3(256), 0, stream,
                           coords, grid, freqs, out, n);
    }
}